// Round 2
// baseline (612.232 us; speedup 1.0000x reference)
//
#include <hip/hip_runtime.h>
#include <hip/hip_cooperative_groups.h>
#include <cstdint>
#include <cstddef>

namespace cg = cooperative_groups;

#define VDIM 50257
#define BNUM 64
#define KNUM 8
#define TITER 20
#define NBLK 512
#define TPB 256
#define SEGN 8
#define SEGLEN 6283              // ceil(V/8); last seg = 6276
#define EPT3 25                  // ceil(SEGLEN/TPB)

// ---- online max/sum-exp helpers -------------------------------------------

__device__ __forceinline__ void onl(float& m, float& s, float x) {
    if (x > m) { s = s * __expf(m - x) + 1.0f; m = x; }
    else       { s += __expf(x - m); }
}

__device__ __forceinline__ void comb(float& m, float& s, float mo, float so) {
    float mn = fmaxf(m, mo);
    s = s * __expf(m - mn) + so * __expf(mo - mn);
    m = mn;
}

__device__ __forceinline__ void blockReduceMS(float& m, float& s, float* shm, int tid) {
    int lane = tid & 63;
    int wid  = tid >> 6;
    #pragma unroll
    for (int off = 32; off > 0; off >>= 1) {
        float mo = __shfl_down(m, off);
        float so = __shfl_down(s, off);
        comb(m, s, mo, so);
    }
    if (lane == 0) { shm[2 * wid] = m; shm[2 * wid + 1] = s; }
    __syncthreads();
    if (tid == 0) {
        float M = shm[0], S = shm[1];
        #pragma unroll
        for (int w = 1; w < 4; w++) comb(M, S, shm[2 * w], shm[2 * w + 1]);
        shm[0] = M; shm[1] = S;
    }
    __syncthreads();
    m = shm[0];
    s = shm[1];
    __syncthreads();
}

__device__ __forceinline__ void blockReduceArgmax(float& v, int& idx, float* shmf, int* shmi, int tid) {
    int lane = tid & 63;
    int wid  = tid >> 6;
    #pragma unroll
    for (int off = 32; off > 0; off >>= 1) {
        float vo = __shfl_down(v, off);
        int   io = __shfl_down(idx, off);
        if (vo > v || (vo == v && io < idx)) { v = vo; idx = io; }
    }
    if (lane == 0) { shmf[wid] = v; shmi[wid] = idx; }
    __syncthreads();
    if (tid == 0) {
        #pragma unroll
        for (int w = 1; w < 4; w++) {
            if (shmf[w] > v || (shmf[w] == v && shmi[w] < idx)) { v = shmf[w]; idx = shmi[w]; }
        }
        shmf[0] = v; shmi[0] = idx;
    }
    __syncthreads();
    v = shmf[0];
    idx = shmi[0];
    __syncthreads();
}

// online stats over one full row of length VDIM, strided by TPB
__device__ __forceinline__ void row_stats(const float* __restrict__ row, int tid,
                                          float& m, float& s) {
    m = -3.0e38f; s = 0.0f;
    int mis  = (int)(((uintptr_t)row & 15) >> 2);
    int head = (4 - mis) & 3;
    if (tid < head) onl(m, s, row[tid]);
    const float4* v4 = (const float4*)(row + head);
    int n4 = (VDIM - head) >> 2;
    for (int g = tid; g < n4; g += TPB) {
        float4 x = v4[g];
        onl(m, s, x.x); onl(m, s, x.y); onl(m, s, x.z); onl(m, s, x.w);
    }
    int done = head + (n4 << 2);
    int j = done + tid;
    if (j < VDIM) onl(m, s, row[j]);
}

// ---- single cooperative kernel --------------------------------------------
// grid: 512 blocks x 256 threads.
// ws float region: p_all[1024] | pm[512] | ps[512] | pv[512]   (2560 floats)
// ws int   region: rp[64] | cnt[64] | rej[64] | pi[512]        (704 ints)

__global__ __launch_bounds__(TPB) void k_coop(
        const float* __restrict__ tgt, const float* __restrict__ bse,
        const float* __restrict__ str,
        const int* __restrict__ draft, const int* __restrict__ ndraft,
        float* __restrict__ out_tok, float* __restrict__ out_cnt,
        float* __restrict__ out_fused,
        float* __restrict__ wsf, int* __restrict__ wsi) {
    cg::grid_group grid = cg::this_grid();
    int blk = blockIdx.x, tid = threadIdx.x;

    __shared__ float shm[16];
    __shared__ int   shmi[8];
    __shared__ float sh_Z;
    __shared__ int   sh_gi;

    float* p_all = wsf;          // [which*512 + r]
    float* pm    = wsf + 1024;
    float* ps    = wsf + 1536;
    float* pv    = wsf + 2048;
    int* rp_arr  = wsi;
    int* cnt_arr = wsi + 64;
    int* rej_arr = wsi + 128;
    int* pi      = wsi + 192;

    // ---- Phase 1: per-row softmax stats (target & base), valid rows only ----
    {
        int r = blk;
        int b1 = r >> 3, k1 = r & (KNUM - 1);
        if (k1 < ndraft[b1]) {           // uniform branch within block
            #pragma unroll
            for (int which = 0; which < 2; which++) {
                const float* row = (which ? bse : tgt) + (size_t)r * VDIM;
                float m, s;
                row_stats(row, tid, m, s);
                blockReduceMS(m, s, shm, tid);
                if (tid == 0) {
                    float lse = m + __logf(s);
                    p_all[which * 512 + r] = __expf(row[draft[r]] - lse);
                }
                __syncthreads();
            }
        }
    }
    __threadfence();
    grid.sync();

    // ---- Phase 2: acceptance chain + token/cnt outputs (block 0) ----
    if (blk == 0 && tid < BNUM) {
        int b = tid;
        int nd = ndraft[b];
        int cnt = 0;
        bool chain = true;
        for (int k = 0; k < KNUM; k++) {
            float pl = p_all[b * KNUM + k];
            float pb = p_all[512 + b * KNUM + k];
            bool acc = (k < nd) && (pl > 0.6f * (pb + 1e-10f));
            chain = chain && acc;
            if (chain) cnt++;
        }
        int rej = (cnt < nd) ? 1 : 0;
        int rp  = cnt < (KNUM - 1) ? cnt : (KNUM - 1);
        for (int k = 0; k < KNUM; k++)
            out_tok[b * (KNUM + 1) + k] = (k < cnt) ? (float)draft[b * KNUM + k] : -1.0f;
        out_tok[b * (KNUM + 1) + KNUM] = -1.0f;   // bonus disabled
        out_cnt[b] = (float)cnt;
        rp_arr[b] = rp; cnt_arr[b] = cnt; rej_arr[b] = rej;
    }
    __threadfence();
    grid.sync();

    // ---- Phase 3: fused pass, 8 segments per request, Y kept in registers ----
    int b   = blk >> 3;
    int seg = blk & (SEGN - 1);
    int rp  = rp_arr[b];
    size_t roff = (size_t)(b * KNUM + rp) * VDIM;
    const float* tl = tgt + roff;
    const float* bl = bse + roff;
    const float* sl = str + roff;

    // Closed-form scalar recurrence (shifts cancel): fused = y - LSE(y),
    // y = aa*tl + bb*(sl-bl).
    float dd = 0.0f, ee = 0.0f, aa = 1.0f, bb = 0.0f;
    #pragma unroll
    for (int t = 1; t <= TITER; t++) {
        dd += 2.0f * (aa - 1.0f);        // ALPHA = 2
        ee += 2.0f * bb + 1.5f;          // ALPHA*b + BETA
        float tf = (float)t;
        float denom = tf * 2.0f + 0.1f;  // t*LAM + 1/ETA
        float an = (tf * 2.0f + dd + aa * 0.1f) / denom;
        float bn = (ee + bb * 0.1f) / denom;
        aa = an; bb = bn;
    }

    int start = seg * SEGLEN;
    int len   = VDIM - start; if (len > SEGLEN) len = SEGLEN;

    float Y[EPT3];
    float m = -3.0e38f, s = 0.0f;
    float bv = -3.0e38f;
    int   bi = 0x7fffffff;
    #pragma unroll
    for (int i = 0; i < EPT3; i++) {
        int j = tid + i * TPB;
        float y = 0.0f;
        if (j < len) {
            int g = start + j;
            y = aa * tl[g] + bb * (sl[g] - bl[g]);
            onl(m, s, y);
            if (y > bv) { bv = y; bi = g; }
        }
        Y[i] = y;
    }
    blockReduceMS(m, s, shm, tid);
    blockReduceArgmax(bv, bi, shm, shmi, tid);
    if (tid == 0) { pm[blk] = m; ps[blk] = s; pv[blk] = bv; pi[blk] = bi; }
    __threadfence();
    grid.sync();

    // ---- Phase 4: combine partials, write normalized output ----
    if (tid == 0) {
        float M = -3.0e38f, S = 0.0f;
        float gv = -3.0e38f;
        int   gi = 0x7fffffff;
        #pragma unroll
        for (int sg = 0; sg < SEGN; sg++) {
            int idx = b * SEGN + sg;
            comb(M, S, pm[idx], ps[idx]);
            float v = pv[idx]; int ii = pi[idx];
            if (v > gv || (v == gv && ii < gi)) { gv = v; gi = ii; }
        }
        sh_Z  = M + __logf(S);
        sh_gi = gi;
    }
    __syncthreads();
    float Z = sh_Z;
    #pragma unroll
    for (int i = 0; i < EPT3; i++) {
        int j = tid + i * TPB;
        if (j < len) out_fused[(size_t)b * VDIM + start + j] = Y[i] - Z;
    }
    if (seg == 0 && tid == 0 && rej_arr[b]) {
        out_tok[b * (KNUM + 1) + cnt_arr[b]] = (float)sh_gi;  // recovered token
    }
}

// ---- host launcher ---------------------------------------------------------

extern "C" void kernel_launch(void* const* d_in, const int* in_sizes, int n_in,
                              void* d_out, int out_size, void* d_ws, size_t ws_size,
                              hipStream_t stream) {
    const float* tgt   = (const float*)d_in[0];
    const float* bse   = (const float*)d_in[1];
    const float* str   = (const float*)d_in[2];
    const int*   draft = (const int*)d_in[3];
    const int*   nd    = (const int*)d_in[4];
    // d_in[5] (bonus_token_ids) unused: ENABLE_BONUS == False

    float* out       = (float*)d_out;
    float* out_tok   = out;                              // 64*9
    float* out_cnt   = out + BNUM * (KNUM + 1);          // 64
    float* out_fused = out + BNUM * (KNUM + 1) + BNUM;   // 64*50257

    float* wsf = (float*)d_ws;                 // 2560 floats
    int*   wsi = (int*)(wsf + 2560);           // 704 ints

    void* args[] = { (void*)&tgt, (void*)&bse, (void*)&str, (void*)&draft,
                     (void*)&nd, (void*)&out_tok, (void*)&out_cnt,
                     (void*)&out_fused, (void*)&wsf, (void*)&wsi };
    hipLaunchCooperativeKernel((const void*)k_coop, dim3(NBLK), dim3(TPB),
                               args, 0, stream);
}

// Round 3
// 273.780 us; speedup vs baseline: 2.2362x; 2.2362x over previous
//
#include <hip/hip_runtime.h>
#include <cstdint>
#include <cstddef>

#define VDIM 50257
#define BNUM 64
#define KNUM 8
#define TITER 20

#define SEGA   12564            // stats segment (mult of 4); 4 segs/row
#define NSEGA  4
#define SEGF   1572             // fused segment (mult of 4); 32 segs/row
#define NSEGF  32
#define EPTF   7                // ceil(1572/256)

// ---- single-exp branchless online max/sum-exp ------------------------------
// if x<=m: s += exp(x-m);  else: s = s*exp(m-x) + 1;  m = max(m,x)
__device__ __forceinline__ void upd(float& m, float& s, float x) {
    float d = m - x;                       // >=0 means x<=m
    float e = __expf(-fabsf(d));
    float t1 = (d >= 0.0f) ? 1.0f : e;
    float t2 = (d >= 0.0f) ? e : 1.0f;
    s = fmaf(s, t1, t2);
    m = fmaxf(m, x);
}

__device__ __forceinline__ void comb(float& m, float& s, float mo, float so) {
    float mn = fmaxf(m, mo);
    s = s * __expf(m - mn) + so * __expf(mo - mn);
    m = mn;
}

// block (m,s) reduction, 4 waves, TPB=256
__device__ __forceinline__ void blockReduceMS(float& m, float& s, float* shm, int tid) {
    int lane = tid & 63, wid = tid >> 6;
    #pragma unroll
    for (int off = 32; off > 0; off >>= 1) {
        float mo = __shfl_down(m, off);
        float so = __shfl_down(s, off);
        comb(m, s, mo, so);
    }
    if (lane == 0) { shm[2 * wid] = m; shm[2 * wid + 1] = s; }
    __syncthreads();
    if (tid == 0) {
        float M = shm[0], S = shm[1];
        #pragma unroll
        for (int w = 1; w < 4; w++) comb(M, S, shm[2 * w], shm[2 * w + 1]);
        shm[0] = M; shm[1] = S;
    }
    __syncthreads();
    m = shm[0]; s = shm[1];
    __syncthreads();
}

__device__ __forceinline__ void blockReduceArgmax(float& v, int& idx, float* shmf, int* shmi, int tid) {
    int lane = tid & 63, wid = tid >> 6;
    #pragma unroll
    for (int off = 32; off > 0; off >>= 1) {
        float vo = __shfl_down(v, off);
        int   io = __shfl_down(idx, off);
        if (vo > v || (vo == v && io < idx)) { v = vo; idx = io; }
    }
    if (lane == 0) { shmf[wid] = v; shmi[wid] = idx; }
    __syncthreads();
    if (tid == 0) {
        #pragma unroll
        for (int w = 1; w < 4; w++)
            if (shmf[w] > v || (shmf[w] == v && shmi[w] < idx)) { v = shmf[w]; idx = shmi[w]; }
        shmf[0] = v; shmi[0] = idx;
    }
    __syncthreads();
    v = shmf[0]; idx = shmi[0];
    __syncthreads();
}

// ---- K1: per-(row,seg) softmax partials; invalid rows early-exit -----------
// grid 4096 = 1024 row-tasks * 4 segs; task = which*512 + r
__global__ __launch_bounds__(256) void k_stats(
        const float* __restrict__ tgt, const float* __restrict__ bse,
        const int* __restrict__ ndraft,
        float* __restrict__ pm_a, float* __restrict__ ps_a) {
    int bid  = blockIdx.x;
    int task = bid >> 2, seg = bid & 3;
    int which = task >> 9, r = task & 511;
    if ((r & 7) >= ndraft[r >> 3]) return;

    const float* row = (which ? bse : tgt) + (size_t)r * VDIM;
    int start = seg * SEGA;
    int len = VDIM - start; if (len > SEGA) len = SEGA;
    const float* p = row + start;
    int tid = threadIdx.x;

    // 4 independent chains for ILP
    float m0 = -3.0e38f, m1 = -3.0e38f, m2 = -3.0e38f, m3 = -3.0e38f;
    float s0 = 0.f, s1 = 0.f, s2 = 0.f, s3 = 0.f;

    int mis  = (int)(((uintptr_t)p & 15) >> 2);
    int head = (4 - mis) & 3;
    if (tid < head) upd(m0, s0, p[tid]);
    const float4* v4 = (const float4*)(p + head);
    int n4 = (len - head) >> 2;
    for (int g = tid; g < n4; g += 256) {
        float4 x = v4[g];
        upd(m0, s0, x.x); upd(m1, s1, x.y); upd(m2, s2, x.z); upd(m3, s3, x.w);
    }
    int j = head + (n4 << 2) + tid;
    if (j < len) upd(m0, s0, p[j]);

    comb(m0, s0, m1, s1);
    comb(m2, s2, m3, s3);
    comb(m0, s0, m2, s2);

    __shared__ float shm[16];
    blockReduceMS(m0, s0, shm, tid);
    if (tid == 0) { pm_a[bid] = m0; ps_a[bid] = s0; }
}

// ---- K2: combine partials + gather p + acceptance --------------------------
// 1 block x 1024 threads
__global__ __launch_bounds__(1024) void k_accept(
        const float* __restrict__ tgt, const float* __restrict__ bse,
        const int* __restrict__ draft, const int* __restrict__ ndraft,
        const float* __restrict__ pm_a, const float* __restrict__ ps_a,
        float* __restrict__ out_tok, float* __restrict__ out_cnt,
        int* __restrict__ rci /* rp[64] | cnt[64] | rej[64] */) {
    __shared__ float shp[1024];
    int t = threadIdx.x;
    int which = t >> 9, r = t & 511;
    int b = r >> 3, k = r & 7;

    float pval = 0.0f;
    if (k < ndraft[b]) {
        float M = -3.0e38f, S = 0.0f;
        #pragma unroll
        for (int sg = 0; sg < NSEGA; sg++) comb(M, S, pm_a[t * 4 + sg], ps_a[t * 4 + sg]);
        float lse = M + __logf(S);
        const float* row = (which ? bse : tgt) + (size_t)r * VDIM;
        pval = __expf(row[draft[r]] - lse);
    }
    shp[t] = pval;
    __syncthreads();

    if (t < BNUM) {
        int nd = ndraft[t];
        int cnt = 0; bool chain = true;
        #pragma unroll
        for (int kk = 0; kk < KNUM; kk++) {
            float pl = shp[t * KNUM + kk];
            float pb = shp[512 + t * KNUM + kk];
            bool acc = (kk < nd) && (pl > 0.6f * (pb + 1e-10f));
            chain = chain && acc;
            if (chain) cnt++;
        }
        int rej = (cnt < nd) ? 1 : 0;
        int rp  = cnt < (KNUM - 1) ? cnt : (KNUM - 1);
        #pragma unroll
        for (int kk = 0; kk < KNUM; kk++)
            out_tok[t * (KNUM + 1) + kk] = (kk < cnt) ? (float)draft[t * KNUM + kk] : -1.0f;
        out_tok[t * (KNUM + 1) + KNUM] = -1.0f;   // bonus disabled
        out_cnt[t] = (float)cnt;
        rci[t] = rp; rci[64 + t] = cnt; rci[128 + t] = rej;
    }
}

// ---- K3: fused-row partial LSE + argmax ------------------------------------
// grid 2048 = 64 b * 32 segs
__global__ __launch_bounds__(256) void k_fpart(
        const float* __restrict__ tgt, const float* __restrict__ bse,
        const float* __restrict__ str, const int* __restrict__ rci,
        float aa, float bb,
        float* __restrict__ pmf, float* __restrict__ psf,
        float* __restrict__ pvf, int* __restrict__ pif) {
    int blk = blockIdx.x;
    int b = blk >> 5, seg = blk & (NSEGF - 1);
    int tid = threadIdx.x;
    int rp = rci[b];
    size_t roff = (size_t)(b * KNUM + rp) * VDIM;
    const float* tl = tgt + roff;
    const float* bl = bse + roff;
    const float* sl = str + roff;

    int start = seg * SEGF;
    int len = VDIM - start; if (len > SEGF) len = SEGF;

    float m = -3.0e38f, s = 0.0f, bv = -3.0e38f;
    int bi = 0x7fffffff;
    #pragma unroll
    for (int i = 0; i < EPTF; i++) {
        int j = tid + i * 256;
        if (j < len) {
            int g = start + j;
            float y = fmaf(aa, tl[g], bb * (sl[g] - bl[g]));
            upd(m, s, y);
            if (y > bv) { bv = y; bi = g; }
        }
    }
    __shared__ float shm[16];
    __shared__ int   shmi[8];
    blockReduceMS(m, s, shm, tid);
    blockReduceArgmax(bv, bi, shm, shmi, tid);
    if (tid == 0) { pmf[blk] = m; psf[blk] = s; pvf[blk] = bv; pif[blk] = bi; }
}

// ---- K4: combine partials, recompute y, write y - Z ------------------------
// grid 2048 = 64 b * 32 segs
__global__ __launch_bounds__(256) void k_final(
        const float* __restrict__ tgt, const float* __restrict__ bse,
        const float* __restrict__ str, const int* __restrict__ rci,
        const float* __restrict__ pmf, const float* __restrict__ psf,
        const float* __restrict__ pvf, const int* __restrict__ pif,
        float aa, float bb,
        float* __restrict__ out_tok, float* __restrict__ out_fused) {
    int blk = blockIdx.x;
    int b = blk >> 5, seg = blk & (NSEGF - 1);
    int tid = threadIdx.x;

    __shared__ float shZ;
    __shared__ int   shG;

    if (tid < 64) {
        float M = -3.0e38f, S = 0.0f, V = -3.0e38f;
        int I = 0x7fffffff;
        if (tid < NSEGF) {
            int idx = b * NSEGF + tid;
            M = pmf[idx]; S = psf[idx]; V = pvf[idx]; I = pif[idx];
        }
        #pragma unroll
        for (int off = 32; off > 0; off >>= 1) {
            float Mo = __shfl_down(M, off);
            float So = __shfl_down(S, off);
            float Vo = __shfl_down(V, off);
            int   Io = __shfl_down(I, off);
            comb(M, S, Mo, So);
            if (Vo > V || (Vo == V && Io < I)) { V = Vo; I = Io; }
        }
        if (tid == 0) { shZ = M + __logf(S); shG = I; }
    }
    __syncthreads();
    float Z = shZ;

    int rp = rci[b];
    size_t roff = (size_t)(b * KNUM + rp) * VDIM;
    const float* tl = tgt + roff;
    const float* bl = bse + roff;
    const float* sl = str + roff;

    int start = seg * SEGF;
    int len = VDIM - start; if (len > SEGF) len = SEGF;
    float* dst = out_fused + (size_t)b * VDIM + start;
    #pragma unroll
    for (int i = 0; i < EPTF; i++) {
        int j = tid + i * 256;
        if (j < len) {
            int g = start + j;
            float y = fmaf(aa, tl[g], bb * (sl[g] - bl[g]));
            dst[j] = y - Z;
        }
    }
    if (seg == 0 && tid == 0 && rci[128 + b]) {
        out_tok[b * (KNUM + 1) + rci[64 + b]] = (float)shG;  // recovered token
    }
}

// ---- host launcher ---------------------------------------------------------

extern "C" void kernel_launch(void* const* d_in, const int* in_sizes, int n_in,
                              void* d_out, int out_size, void* d_ws, size_t ws_size,
                              hipStream_t stream) {
    const float* tgt   = (const float*)d_in[0];
    const float* bse   = (const float*)d_in[1];
    const float* str   = (const float*)d_in[2];
    const int*   draft = (const int*)d_in[3];
    const int*   nd    = (const int*)d_in[4];

    float* out       = (float*)d_out;
    float* out_tok   = out;                              // 64*9
    float* out_cnt   = out + BNUM * (KNUM + 1);          // 64
    float* out_fused = out + BNUM * (KNUM + 1) + BNUM;   // 64*50257

    float* wsf  = (float*)d_ws;
    float* pm_a = wsf;                 // 4096
    float* ps_a = wsf + 4096;          // 4096
    float* pmf  = wsf + 8192;          // 2048
    float* psf  = wsf + 10240;         // 2048
    float* pvf  = wsf + 12288;         // 2048
    int*   wsi  = (int*)(wsf + 14336);
    int*   rci  = wsi;                 // 192
    int*   pif  = wsi + 192;           // 2048

    // Closed-form co-steer recurrence: fused = y - LSE(y), y = aa*tl + bb*(sl-bl).
    // All log-softmax shifts cancel; only (aa,bb) survive. Same float arithmetic
    // as the verified R1 in-kernel loop.
    float dd = 0.0f, ee = 0.0f, aa = 1.0f, bb = 0.0f;
    for (int t = 1; t <= TITER; t++) {
        dd += 2.0f * (aa - 1.0f);
        ee += 2.0f * bb + 1.5f;
        float tf = (float)t;
        float denom = tf * 2.0f + 0.1f;
        float an = (tf * 2.0f + dd + aa * 0.1f) / denom;
        float bn = (ee + bb * 0.1f) / denom;
        aa = an; bb = bn;
    }

    hipLaunchKernelGGL(k_stats, dim3(1024 * NSEGA), dim3(256), 0, stream,
                       tgt, bse, nd, pm_a, ps_a);
    hipLaunchKernelGGL(k_accept, dim3(1), dim3(1024), 0, stream,
                       tgt, bse, draft, nd, pm_a, ps_a, out_tok, out_cnt, rci);
    hipLaunchKernelGGL(k_fpart, dim3(BNUM * NSEGF), dim3(256), 0, stream,
                       tgt, bse, str, rci, aa, bb, pmf, psf, pvf, pif);
    hipLaunchKernelGGL(k_final, dim3(BNUM * NSEGF), dim3(256), 0, stream,
                       tgt, bse, str, rci, pmf, psf, pvf, pif, aa, bb,
                       out_tok, out_fused);
}

// Round 4
// 268.950 us; speedup vs baseline: 2.2764x; 1.0180x over previous
//
#include <hip/hip_runtime.h>
#include <cstdint>
#include <cstddef>

#define VDIM 50257
#define BNUM 64
#define KNUM 8
#define TITER 20

#define SEGA   12564            // stats segment (mult of 4); 4 segs/row
#define NSEGA  4
#define SEGF   1572             // fused segment (mult of 4); 32 segs/row
#define NSEGF  32
#define EPTF   7                // ceil(1572/256)
#define SEGS   6284             // subtract segment (mult of 4); 8 segs/row
#define NSEGS  8

// ---- single-exp branchless online max/sum-exp ------------------------------
// if x<=m: s += exp(x-m);  else: s = s*exp(m-x) + 1;  m = max(m,x)
__device__ __forceinline__ void upd(float& m, float& s, float x) {
    float d = m - x;                       // >=0 means x<=m
    float e = __expf(-fabsf(d));
    float t1 = (d >= 0.0f) ? 1.0f : e;
    float t2 = (d >= 0.0f) ? e : 1.0f;
    s = fmaf(s, t1, t2);
    m = fmaxf(m, x);
}

__device__ __forceinline__ void comb(float& m, float& s, float mo, float so) {
    float mn = fmaxf(m, mo);
    s = s * __expf(m - mn) + so * __expf(mo - mn);
    m = mn;
}

// block (m,s) reduction, 4 waves, TPB=256
__device__ __forceinline__ void blockReduceMS(float& m, float& s, float* shm, int tid) {
    int lane = tid & 63, wid = tid >> 6;
    #pragma unroll
    for (int off = 32; off > 0; off >>= 1) {
        float mo = __shfl_down(m, off);
        float so = __shfl_down(s, off);
        comb(m, s, mo, so);
    }
    if (lane == 0) { shm[2 * wid] = m; shm[2 * wid + 1] = s; }
    __syncthreads();
    if (tid == 0) {
        float M = shm[0], S = shm[1];
        #pragma unroll
        for (int w = 1; w < 4; w++) comb(M, S, shm[2 * w], shm[2 * w + 1]);
        shm[0] = M; shm[1] = S;
    }
    __syncthreads();
    m = shm[0]; s = shm[1];
    __syncthreads();
}

__device__ __forceinline__ void blockReduceArgmax(float& v, int& idx, float* shmf, int* shmi, int tid) {
    int lane = tid & 63, wid = tid >> 6;
    #pragma unroll
    for (int off = 32; off > 0; off >>= 1) {
        float vo = __shfl_down(v, off);
        int   io = __shfl_down(idx, off);
        if (vo > v || (vo == v && io < idx)) { v = vo; idx = io; }
    }
    if (lane == 0) { shmf[wid] = v; shmi[wid] = idx; }
    __syncthreads();
    if (tid == 0) {
        #pragma unroll
        for (int w = 1; w < 4; w++)
            if (shmf[w] > v || (shmf[w] == v && shmi[w] < idx)) { v = shmf[w]; idx = shmi[w]; }
        shmf[0] = v; shmi[0] = idx;
    }
    __syncthreads();
    v = shmf[0]; idx = shmi[0];
    __syncthreads();
}

// ---- K1: per-(row,seg) softmax partials; invalid rows early-exit -----------
// grid 4096 = 1024 row-tasks * 4 segs; task = which*512 + r
__global__ __launch_bounds__(256) void k_stats(
        const float* __restrict__ tgt, const float* __restrict__ bse,
        const int* __restrict__ ndraft,
        float* __restrict__ pm_a, float* __restrict__ ps_a) {
    int bid  = blockIdx.x;
    int task = bid >> 2, seg = bid & 3;
    int which = task >> 9, r = task & 511;
    if ((r & 7) >= ndraft[r >> 3]) return;

    const float* row = (which ? bse : tgt) + (size_t)r * VDIM;
    int start = seg * SEGA;
    int len = VDIM - start; if (len > SEGA) len = SEGA;
    const float* p = row + start;
    int tid = threadIdx.x;

    // 4 independent chains for ILP
    float m0 = -3.0e38f, m1 = -3.0e38f, m2 = -3.0e38f, m3 = -3.0e38f;
    float s0 = 0.f, s1 = 0.f, s2 = 0.f, s3 = 0.f;

    int mis  = (int)(((uintptr_t)p & 15) >> 2);
    int head = (4 - mis) & 3;
    if (tid < head) upd(m0, s0, p[tid]);
    const float4* v4 = (const float4*)(p + head);
    int n4 = (len - head) >> 2;
    for (int g = tid; g < n4; g += 256) {
        float4 x = v4[g];
        upd(m0, s0, x.x); upd(m1, s1, x.y); upd(m2, s2, x.z); upd(m3, s3, x.w);
    }
    int j = head + (n4 << 2) + tid;
    if (j < len) upd(m0, s0, p[j]);

    comb(m0, s0, m1, s1);
    comb(m2, s2, m3, s3);
    comb(m0, s0, m2, s2);

    __shared__ float shm[16];
    blockReduceMS(m0, s0, shm, tid);
    if (tid == 0) { pm_a[bid] = m0; ps_a[bid] = s0; }
}

// ---- K2: redundant per-block acceptance + fused y write + partial LSE/argmax
// grid 2048 = 64 b * 32 segs
__global__ __launch_bounds__(256) void k_fused(
        const float* __restrict__ tgt, const float* __restrict__ bse,
        const float* __restrict__ str,
        const int* __restrict__ draft, const int* __restrict__ ndraft,
        const float* __restrict__ pm_a, const float* __restrict__ ps_a,
        float aa, float bb,
        float* __restrict__ out_tok, float* __restrict__ out_cnt,
        float* __restrict__ out_fused, int* __restrict__ rci,
        float* __restrict__ pmf, float* __restrict__ psf,
        float* __restrict__ pvf, int* __restrict__ pif) {
    int blk = blockIdx.x;
    int b = blk >> 5, seg = blk & (NSEGF - 1);
    int tid = threadIdx.x;

    __shared__ float shp[16];
    __shared__ float shm[16];
    __shared__ int   shmi[8];
    __shared__ int   sh_rp;

    int nd = ndraft[b];

    // acceptance prologue: combine k_stats partials, gather p_llm/p_base
    if (tid < 16) {
        int which = tid >> 3, k = tid & 7, r = b * KNUM + k;
        float pval = 0.0f;
        if (k < nd) {                       // guard: invalid rows have no partials
            float M = -3.0e38f, S = 0.0f;
            int base = (which * 512 + r) * NSEGA;
            #pragma unroll
            for (int sg = 0; sg < NSEGA; sg++) comb(M, S, pm_a[base + sg], ps_a[base + sg]);
            float lse = M + __logf(S);
            const float* row = (which ? bse : tgt) + (size_t)r * VDIM;
            pval = __expf(row[draft[r]] - lse);   // L3-hot gather
        }
        shp[tid] = pval;
    }
    __syncthreads();
    if (tid == 0) {
        int cnt = 0; bool chain = true;
        #pragma unroll
        for (int kk = 0; kk < KNUM; kk++) {
            float pl = shp[kk], pb = shp[8 + kk];
            bool acc = (kk < nd) && (pl > 0.6f * (pb + 1e-10f));
            chain = chain && acc;
            if (chain) cnt++;
        }
        int rej = (cnt < nd) ? 1 : 0;
        int rp  = cnt < (KNUM - 1) ? cnt : (KNUM - 1);
        sh_rp = rp;
        if (seg == 0) {
            #pragma unroll
            for (int kk = 0; kk < KNUM; kk++)
                out_tok[b * (KNUM + 1) + kk] = (kk < cnt) ? (float)draft[b * KNUM + kk] : -1.0f;
            out_tok[b * (KNUM + 1) + KNUM] = -1.0f;   // bonus disabled
            out_cnt[b] = (float)cnt;
            rci[b] = rp; rci[64 + b] = cnt; rci[128 + b] = rej;
        }
    }
    __syncthreads();
    int rp = sh_rp;

    size_t roff = (size_t)(b * KNUM + rp) * VDIM;
    const float* tl = tgt + roff;
    const float* bl = bse + roff;
    const float* sl = str + roff;

    int start = seg * SEGF;
    int len = VDIM - start; if (len > SEGF) len = SEGF;
    float* dst = out_fused + (size_t)b * VDIM + start;

    float m = -3.0e38f, s = 0.0f, bv = -3.0e38f;
    int bi = 0x7fffffff;
    #pragma unroll
    for (int i = 0; i < EPTF; i++) {
        int j = tid + i * 256;
        if (j < len) {
            int g = start + j;
            float y = fmaf(aa, tl[g], bb * (sl[g] - bl[g]));
            dst[j] = y;                     // unnormalized; K3 subtracts Z
            upd(m, s, y);
            if (y > bv) { bv = y; bi = g; }
        }
    }
    blockReduceMS(m, s, shm, tid);
    blockReduceArgmax(bv, bi, shm, shmi, tid);
    if (tid == 0) { pmf[blk] = m; psf[blk] = s; pvf[blk] = bv; pif[blk] = bi; }
}

// ---- K3: combine partials, RMW subtract Z (float4), recovered token --------
// grid 512 = 64 b * 8 segs
__global__ __launch_bounds__(256) void k_sub(
        const int* __restrict__ rci,
        const float* __restrict__ pmf, const float* __restrict__ psf,
        const float* __restrict__ pvf, const int* __restrict__ pif,
        float* __restrict__ out_tok, float* __restrict__ out_fused) {
    int blk = blockIdx.x;
    int b = blk >> 3, seg = blk & (NSEGS - 1);
    int tid = threadIdx.x;

    __shared__ float shZ;
    __shared__ int   shG;

    if (tid < 64) {
        float M = -3.0e38f, S = 0.0f, V = -3.0e38f;
        int I = 0x7fffffff;
        if (tid < NSEGF) {
            int idx = b * NSEGF + tid;
            M = pmf[idx]; S = psf[idx]; V = pvf[idx]; I = pif[idx];
        }
        #pragma unroll
        for (int off = 16; off > 0; off >>= 1) {
            float Mo = __shfl_down(M, off);
            float So = __shfl_down(S, off);
            float Vo = __shfl_down(V, off);
            int   Io = __shfl_down(I, off);
            comb(M, S, Mo, So);
            if (Vo > V || (Vo == V && Io < I)) { V = Vo; I = Io; }
        }
        if (tid == 0) { shZ = M + __logf(S); shG = I; }
    }
    __syncthreads();
    float Z = shZ;

    int start = seg * SEGS;
    int len = VDIM - start; if (len > SEGS) len = SEGS;
    float* p = out_fused + (size_t)b * VDIM + start;

    int mis  = (int)(((uintptr_t)p & 15) >> 2);
    int head = (4 - mis) & 3;
    if (head > len) head = len;
    if (tid < head) p[tid] -= Z;
    float4* v4 = (float4*)(p + head);
    int n4 = (len - head) >> 2;
    for (int g = tid; g < n4; g += 256) {
        float4 x = v4[g];
        x.x -= Z; x.y -= Z; x.z -= Z; x.w -= Z;
        v4[g] = x;
    }
    int j = head + (n4 << 2) + tid;
    if (j < len) p[j] -= Z;

    if (seg == 0 && tid == 0 && rci[128 + b]) {
        out_tok[b * (KNUM + 1) + rci[64 + b]] = (float)shG;  // recovered token
    }
}

// ---- host launcher ---------------------------------------------------------

extern "C" void kernel_launch(void* const* d_in, const int* in_sizes, int n_in,
                              void* d_out, int out_size, void* d_ws, size_t ws_size,
                              hipStream_t stream) {
    const float* tgt   = (const float*)d_in[0];
    const float* bse   = (const float*)d_in[1];
    const float* str   = (const float*)d_in[2];
    const int*   draft = (const int*)d_in[3];
    const int*   nd    = (const int*)d_in[4];

    float* out       = (float*)d_out;
    float* out_tok   = out;                              // 64*9
    float* out_cnt   = out + BNUM * (KNUM + 1);          // 64
    float* out_fused = out + BNUM * (KNUM + 1) + BNUM;   // 64*50257

    float* wsf  = (float*)d_ws;
    float* pm_a = wsf;                 // 4096
    float* ps_a = wsf + 4096;          // 4096
    float* pmf  = wsf + 8192;          // 2048
    float* psf  = wsf + 10240;         // 2048
    float* pvf  = wsf + 12288;         // 2048
    int*   wsi  = (int*)(wsf + 14336);
    int*   rci  = wsi;                 // 192
    int*   pif  = wsi + 192;           // 2048

    // Closed-form co-steer recurrence: fused = y - LSE(y), y = aa*tl + bb*(sl-bl).
    // All log-softmax shifts cancel; only (aa,bb) survive (verified R1-R3).
    float dd = 0.0f, ee = 0.0f, aa = 1.0f, bb = 0.0f;
    for (int t = 1; t <= TITER; t++) {
        dd += 2.0f * (aa - 1.0f);
        ee += 2.0f * bb + 1.5f;
        float tf = (float)t;
        float denom = tf * 2.0f + 0.1f;
        float an = (tf * 2.0f + dd + aa * 0.1f) / denom;
        float bn = (ee + bb * 0.1f) / denom;
        aa = an; bb = bn;
    }

    hipLaunchKernelGGL(k_stats, dim3(1024 * NSEGA), dim3(256), 0, stream,
                       tgt, bse, nd, pm_a, ps_a);
    hipLaunchKernelGGL(k_fused, dim3(BNUM * NSEGF), dim3(256), 0, stream,
                       tgt, bse, str, draft, nd, pm_a, ps_a, aa, bb,
                       out_tok, out_cnt, out_fused, rci, pmf, psf, pvf, pif);
    hipLaunchKernelGGL(k_sub, dim3(BNUM * NSEGS), dim3(256), 0, stream,
                       rci, pmf, psf, pvf, pif, out_tok, out_fused);
}